// Round 8
// baseline (280.959 us; speedup 1.0000x reference)
//
#include <hip/hip_runtime.h>
#include <hip/hip_bf16.h>

// Problem: out[b,j,k] = squash_j( s[b,j,k] ), s = sum_{i<2048,u<16} W[i,j,k,u] x[b,u,i]
// GEMM view: C[m=b(32), n=(j,k)(1024)] = A[m,(i,u)] B[(i,u),n], K=32768.
// W[i][j][k][u] strides (floats): i:16384, j:1024, k:16, u:1
// x[b][u][i]    strides (floats): b:32768, u:2048, i:1
//
// R8 = DIAGNOSTIC round. Identical to R7 except caps_mfma runs its K-loop
// FOUR passes over the same W range (nontemporal loads so passes 2-4
// re-stream from HBM, not L3) and scales acc by 0.25 in the epilogue
// (exact-enough: extra rounding << 1/256 tolerance). Purpose: push
// caps_mfma's duration past the ~78us harness poison-fills so its rocprof
// counters (hbm_gbps / MfmaUtil / VALUBusy / FETCH_SIZE) finally appear in
// the top-5 — discriminating "mfma already at 21us stream floor" from
// "mfma throttled at ~4TB/s". dur_us of this round is sacrificial.

#define B_SZ   32
#define IC     2048
#define NJ     16
#define NK     64
#define SOUT   (B_SZ*NJ*NK)      // 32768
#define KSTEPS 1024              // K-steps; each covers kdim=32 = (2 i's x 16 u)
#define KSPLIT 32                // K-splits (grid = NJ x KSPLIT = 512 blocks)
#define SPW    (KSTEPS/KSPLIT)   // 32 steps per block
#define NPASS  4                 // diagnostic repeat count

typedef float  v4f __attribute__((ext_vector_type(4)));
typedef short  v8s __attribute__((ext_vector_type(8)));
typedef uint   v4u __attribute__((ext_vector_type(4)));

// pack 2 f32 -> 1 dword of 2 bf16 (RNE); lowers to v_cvt_pk_bf16_f32
static __device__ inline uint pk2(float a, float b) {
    __hip_bfloat162 h = __float22bfloat162_rn(make_float2(a, b));
    uint r;
    __builtin_memcpy(&r, &h, 4);
    return r;
}

// ---------------------------------------------------------------------------
// xprep v2 (unchanged from R7): full-line x reads + LDS transpose, coalesced
// xb writes. xb flat: [step(1024)][mt(2)][lane(64)][jj(8)] bf16.
// ---------------------------------------------------------------------------
__global__ __launch_bounds__(256)
void caps_xprep(const float* __restrict__ x, ushort* __restrict__ xb) {
    __shared__ ushort tile[256 * 18];    // 9 KB
    const int t  = threadIdx.x;
    const int i0 = blockIdx.x * 16;      // 0..2032
    const int mt = blockIdx.y;           // 0..1

    {
        const int r2 = t;                          // row = b_local*16 + u
        const float* xp = x + (size_t)(mt * 256 + r2) * IC + i0;
        v4f f0 = *(const v4f*)(xp);
        v4f f1 = *(const v4f*)(xp + 4);
        v4f f2 = *(const v4f*)(xp + 8);
        v4f f3 = *(const v4f*)(xp + 12);
        uint d[8] = {pk2(f0.x, f0.y), pk2(f0.z, f0.w), pk2(f1.x, f1.y), pk2(f1.z, f1.w),
                     pk2(f2.x, f2.y), pk2(f2.z, f2.w), pk2(f3.x, f3.y), pk2(f3.z, f3.w)};
        const int swz = ((r2 >> 3) & 7) << 1;      // even -> dword pairs stay intact
        #pragma unroll
        for (int c = 0; c < 8; ++c)
            *(uint*)&tile[r2 * 18 + ((2 * c) ^ swz)] = d[c];
    }
    __syncthreads();

    #pragma unroll
    for (int rr = 0; rr < 2; ++rr) {
        const int idx   = rr * 256 + t;
        const int stepl = idx >> 6;                // 0..7
        const int lane  = idx & 63;
        const int q  = lane >> 4;
        const int bl = lane & 15;
        const int il = 2 * stepl + (q >> 1);       // 0..15
        const int rb = bl * 16 + (q & 1) * 8;      // row base (mult of 8)
        const int swz = ((rb >> 3) & 7) << 1;      // constant over jj
        ushort v[8];
        #pragma unroll
        for (int jj = 0; jj < 8; ++jj)
            v[jj] = tile[(rb + jj) * 18 + (il ^ swz)];
        const int stepg = blockIdx.x * 8 + stepl;
        *(v8s*)(xb + (size_t)stepg * 1024 + mt * 512 + lane * 8) = *(const v8s*)v;
    }
}

// ---------------------------------------------------------------------------
// main (DIAGNOSTIC x4): R0/R7 core, K-loop repeated NPASS times over the same
// W range (nontemporal so each pass streams from HBM), acc *= 1/NPASS.
// ---------------------------------------------------------------------------
__global__ __launch_bounds__(256)
void caps_mfma(const ushort* __restrict__ xb, const float* __restrict__ W,
               float* __restrict__ part) {
    const int tid   = threadIdx.x;
    const int wv    = tid >> 6;       // k'-tile 0..3
    const int lane  = tid & 63;
    const int j     = blockIdx.x;     // 0..15
    const int split = blockIdx.y;     // 0..KSPLIT-1
    const int n     = lane & 15;
    const int q     = lane >> 4;
    const int step0 = split * SPW;

    v4f acc0 = {0.f, 0.f, 0.f, 0.f};
    v4f acc1 = {0.f, 0.f, 0.f, 0.f};

    const float*  wbase = W + (size_t)(2 * step0 + (q >> 1)) * 16384
                            + (size_t)j * 1024 + (size_t)(wv * 16 + n) * 16 + (q & 1) * 8;
    const ushort* xbase = xb + (size_t)step0 * 1024 + (size_t)lane * 8;

    for (int p = 0; p < NPASS; ++p) {
        const float*  wp = wbase;
        const ushort* xp = xbase;
        #pragma unroll 4
        for (int s = 0; s < SPW; ++s) {
            v4f w0 = __builtin_nontemporal_load((const v4f*)wp);
            v4f w1 = __builtin_nontemporal_load(((const v4f*)wp) + 1);
            v8s a0 = *(const v8s*)(xp);          // b-tile 0 (b 0..15)
            v8s a1 = *(const v8s*)(xp + 512);    // b-tile 1 (b 16..31)
            v4u bu;
            bu[0] = pk2(w0.x, w0.y);
            bu[1] = pk2(w0.z, w0.w);
            bu[2] = pk2(w1.x, w1.y);
            bu[3] = pk2(w1.z, w1.w);
            v8s bb;
            __builtin_memcpy(&bb, &bu, 16);
            acc0 = __builtin_amdgcn_mfma_f32_16x16x32_bf16(a0, bb, acc0, 0, 0, 0);
            acc1 = __builtin_amdgcn_mfma_f32_16x16x32_bf16(a1, bb, acc1, 0, 0, 0);
            wp += 2 * 16384;
            xp += 1024;
        }
    }

    const float sc = 1.0f / NPASS;
    acc0 *= sc;
    acc1 *= sc;

    // C/D layout: col = lane&15 = n (k'), row = q*4 + reg = m (b).
    // part[split][b][j][k] : k = wv*16 + n
    float* pp = part + (size_t)split * SOUT + (size_t)j * NK + wv * 16 + n;
    #pragma unroll
    for (int r = 0; r < 4; ++r) {
        int m = q * 4 + r;
        pp[(size_t)m * 1024]        = acc0[r];
        pp[(size_t)(m + 16) * 1024] = acc1[r];
    }
}

// ---------------------------------------------------------------------------
// finish (unchanged from R7): sum K-splits + squash over j, 512 blocks.
// ---------------------------------------------------------------------------
__global__ __launch_bounds__(256)
void caps_finish(const float* __restrict__ part, float* __restrict__ out) {
    __shared__ float ls[256];
    __shared__ float l2[64];
    const int bid = blockIdx.x;
    const int b   = bid >> 4;
    const int k0  = (bid & 15) * 4;
    const int tid = threadIdx.x;
    const int jj  = tid >> 4;
    const int kc  = (tid >> 2) & 3;
    const int sg  = tid & 3;
    const size_t idx = (size_t)b * 1024 + (size_t)jj * NK + k0 + kc;

    float s = 0.0f;
    #pragma unroll
    for (int ss = 0; ss < KSPLIT / 4; ++ss)
        s += part[(size_t)(sg + 4 * ss) * SOUT + idx];
    ls[tid] = s;
    __syncthreads();

    if (sg == 0)
        l2[jj * 4 + kc] = ls[tid] + ls[tid + 1] + ls[tid + 2] + ls[tid + 3];
    __syncthreads();

    if (sg == 0) {
        float sa  = l2[jj * 4 + kc];
        float msq = 0.0f;
        #pragma unroll
        for (int j2 = 0; j2 < NJ; ++j2) {
            float v = l2[j2 * 4 + kc];
            msq += v * v;
        }
        float mag = sqrtf(msq);
        out[idx] = sa * (mag / (1.0f + msq));
    }
}

extern "C" void kernel_launch(void* const* d_in, const int* in_sizes, int n_in,
                              void* d_out, int out_size, void* d_ws, size_t ws_size,
                              hipStream_t stream) {
    const float* x = (const float*)d_in[0];   // (32, 16, 2048) f32
    const float* W = (const float*)d_in[1];   // (1, 2048, 16, 64, 16) f32
    float* out  = (float*)d_out;              // (32, 16, 64) f32

    float*  part = (float*)d_ws;                            // 4 MB
    ushort* xb   = (ushort*)(part + (size_t)KSPLIT * SOUT); // 2 MB

    caps_xprep <<<dim3(128, 2),     256, 0, stream>>>(x, xb);
    caps_mfma  <<<dim3(NJ, KSPLIT), 256, 0, stream>>>(xb, W, part);
    caps_finish<<<512,              256, 0, stream>>>(part, out);
}

// Round 9
// 215.231 us; speedup vs baseline: 1.3054x; 1.3054x over previous
//
#include <hip/hip_runtime.h>
#include <hip/hip_bf16.h>

// Problem: out[b,j,k] = squash_j( s[b,j,k] ), s = sum_{i<2048,u<16} W[i,j,k,u] x[b,u,i]
// GEMM view: C[m=b(32), n=(j,k)(1024)] = A[m,(i,u)] B[(i,u),n], K=32768.
// W[i][j][k][u] strides (floats): i:16384, j:1024, k:16, u:1
// x[b][u][i]    strides (floats): b:32768, u:2048, i:1
//
// R9: R8's diagnostic showed caps_mfma is CONCURRENCY-starved (occupancy 18%,
// HBM 30%, MfmaUtil 2.8%, consumption capped at 4.6 TB/s from HBM+L3 alike).
// Fix: 4x the in-flight memory — KSPLIT=128 x JPB=2 -> 1024 blocks (4/CU,
// 16 waves/CU) and 4 W-loads in flight per wave per step. Plain loads (no nt:
// W is half-L3-resident across iterations; nt would force HBM re-fetch).
// xprep/finish keep R7's proven forms; part grows to 16 MB (accepted ~2-3us).

#define B_SZ   32
#define IC     2048
#define NJ     16
#define NK     64
#define SOUT   (B_SZ*NJ*NK)      // 32768
#define KSTEPS 1024              // K-steps; each covers kdim=32 = (2 i's x 16 u)
#define KSPLIT 128               // K-splits (grid.y)
#define SPW    (KSTEPS/KSPLIT)   // 8 steps per block
#define JPB    2                 // j's per block (grid.x = 8)

typedef float  v4f __attribute__((ext_vector_type(4)));
typedef short  v8s __attribute__((ext_vector_type(8)));
typedef uint   v4u __attribute__((ext_vector_type(4)));

// pack 2 f32 -> 1 dword of 2 bf16 (RNE); lowers to v_cvt_pk_bf16_f32
static __device__ inline uint pk2(float a, float b) {
    __hip_bfloat162 h = __float22bfloat162_rn(make_float2(a, b));
    uint r;
    __builtin_memcpy(&r, &h, 4);
    return r;
}

// ---------------------------------------------------------------------------
// xprep v2 (unchanged from R7): full-line x reads + LDS transpose, coalesced
// xb writes. xb flat: [step(1024)][mt(2)][lane(64)][jj(8)] bf16; value =
//   bf16( x[b = mt*16+(lane&15)][u = (q&1)*8+jj][i = 2*step+(q>>1)] ), q=lane>>4.
// ---------------------------------------------------------------------------
__global__ __launch_bounds__(256)
void caps_xprep(const float* __restrict__ x, ushort* __restrict__ xb) {
    __shared__ ushort tile[256 * 18];    // 9 KB
    const int t  = threadIdx.x;
    const int i0 = blockIdx.x * 16;      // 0..2032
    const int mt = blockIdx.y;           // 0..1

    {
        const int r2 = t;                          // row = b_local*16 + u
        const float* xp = x + (size_t)(mt * 256 + r2) * IC + i0;
        v4f f0 = *(const v4f*)(xp);
        v4f f1 = *(const v4f*)(xp + 4);
        v4f f2 = *(const v4f*)(xp + 8);
        v4f f3 = *(const v4f*)(xp + 12);
        uint d[8] = {pk2(f0.x, f0.y), pk2(f0.z, f0.w), pk2(f1.x, f1.y), pk2(f1.z, f1.w),
                     pk2(f2.x, f2.y), pk2(f2.z, f2.w), pk2(f3.x, f3.y), pk2(f3.z, f3.w)};
        const int swz = ((r2 >> 3) & 7) << 1;      // even -> dword pairs stay intact
        #pragma unroll
        for (int c = 0; c < 8; ++c)
            *(uint*)&tile[r2 * 18 + ((2 * c) ^ swz)] = d[c];
    }
    __syncthreads();

    #pragma unroll
    for (int rr = 0; rr < 2; ++rr) {
        const int idx   = rr * 256 + t;
        const int stepl = idx >> 6;                // 0..7
        const int lane  = idx & 63;
        const int q  = lane >> 4;
        const int bl = lane & 15;
        const int il = 2 * stepl + (q >> 1);       // 0..15
        const int rb = bl * 16 + (q & 1) * 8;      // row base (mult of 8)
        const int swz = ((rb >> 3) & 7) << 1;      // constant over jj
        ushort v[8];
        #pragma unroll
        for (int jj = 0; jj < 8; ++jj)
            v[jj] = tile[(rb + jj) * 18 + (il ^ swz)];
        const int stepg = blockIdx.x * 8 + stepl;
        *(v8s*)(xb + (size_t)stepg * 1024 + mt * 512 + lane * 8) = *(const v8s*)v;
    }
}

// ---------------------------------------------------------------------------
// main: block = (jp, split), 256 thr = 4 waves; wave wv = k'-tile (16 k's).
// Covers TWO j's: per K-step 4 W dwordx4 in flight (4 KB/wave), 2 xb dwordx4,
// cvt_pk -> 2 B-frags, 4 MFMA. Grid 8x128 = 1024 blocks = 4/CU = 16 waves/CU.
// B-operand layout: lane holds B[kk = (lane>>4)*8 + jj][n = lane&15];
//   W addr: i = 2*step + (q>>1), u = (q&1)*8 + jj (8 consecutive floats).
// ---------------------------------------------------------------------------
__global__ __launch_bounds__(256)
void caps_mfma(const ushort* __restrict__ xb, const float* __restrict__ W,
               float* __restrict__ part) {
    const int tid   = threadIdx.x;
    const int wv    = tid >> 6;          // k'-tile 0..3
    const int lane  = tid & 63;
    const int j0    = blockIdx.x * JPB;  // 0,2,..,14
    const int split = blockIdx.y;        // 0..KSPLIT-1
    const int n     = lane & 15;
    const int q     = lane >> 4;
    const int step0 = split * SPW;

    v4f acc00 = {0.f, 0.f, 0.f, 0.f};   // j0, b 0..15
    v4f acc01 = {0.f, 0.f, 0.f, 0.f};   // j0, b 16..31
    v4f acc10 = {0.f, 0.f, 0.f, 0.f};   // j1, b 0..15
    v4f acc11 = {0.f, 0.f, 0.f, 0.f};   // j1, b 16..31

    const float*  wp = W + (size_t)(2 * step0 + (q >> 1)) * 16384
                         + (size_t)j0 * 1024 + (size_t)(wv * 16 + n) * 16 + (q & 1) * 8;
    const ushort* xp = xb + (size_t)step0 * 1024 + (size_t)lane * 8;

    #pragma unroll 4
    for (int s = 0; s < SPW; ++s) {
        v4f w00 = *(const v4f*)(wp);
        v4f w01 = *(const v4f*)(wp + 4);
        v4f w10 = *(const v4f*)(wp + 1024);
        v4f w11 = *(const v4f*)(wp + 1028);
        v8s a0 = *(const v8s*)(xp);          // b-tile 0 (b 0..15)
        v8s a1 = *(const v8s*)(xp + 512);    // b-tile 1 (b 16..31)
        v4u bu0, bu1;
        bu0[0] = pk2(w00.x, w00.y);
        bu0[1] = pk2(w00.z, w00.w);
        bu0[2] = pk2(w01.x, w01.y);
        bu0[3] = pk2(w01.z, w01.w);
        bu1[0] = pk2(w10.x, w10.y);
        bu1[1] = pk2(w10.z, w10.w);
        bu1[2] = pk2(w11.x, w11.y);
        bu1[3] = pk2(w11.z, w11.w);
        v8s b0, b1;
        __builtin_memcpy(&b0, &bu0, 16);
        __builtin_memcpy(&b1, &bu1, 16);
        acc00 = __builtin_amdgcn_mfma_f32_16x16x32_bf16(a0, b0, acc00, 0, 0, 0);
        acc01 = __builtin_amdgcn_mfma_f32_16x16x32_bf16(a1, b0, acc01, 0, 0, 0);
        acc10 = __builtin_amdgcn_mfma_f32_16x16x32_bf16(a0, b1, acc10, 0, 0, 0);
        acc11 = __builtin_amdgcn_mfma_f32_16x16x32_bf16(a1, b1, acc11, 0, 0, 0);
        wp += 2 * 16384;
        xp += 1024;
    }

    // C/D layout: col = lane&15 = n (k'), row = q*4 + reg = m (b).
    // part[split][b][j][k] : k = wv*16 + n ; j1 is +NK floats from j0.
    float* pp = part + (size_t)split * SOUT + (size_t)j0 * NK + wv * 16 + n;
    #pragma unroll
    for (int r = 0; r < 4; ++r) {
        int m = q * 4 + r;
        pp[(size_t)m * 1024]             = acc00[r];
        pp[(size_t)(m + 16) * 1024]      = acc01[r];
        pp[(size_t)m * 1024 + NK]        = acc10[r];
        pp[(size_t)(m + 16) * 1024 + NK] = acc11[r];
    }
}

// ---------------------------------------------------------------------------
// finish (R7 form, KSPLIT=128): sum K-splits + squash over j, 512 blocks.
// block -> (b = bid>>4, k0 = (bid&15)*4); thread -> (jj = tid>>4,
// kc = (tid>>2)&3, sg = tid&3). Each thread sums KSPLIT/4 = 32 splits ->
// LDS reduce over sg -> squash over jj.
// ---------------------------------------------------------------------------
__global__ __launch_bounds__(256)
void caps_finish(const float* __restrict__ part, float* __restrict__ out) {
    __shared__ float ls[256];
    __shared__ float l2[64];
    const int bid = blockIdx.x;
    const int b   = bid >> 4;
    const int k0  = (bid & 15) * 4;
    const int tid = threadIdx.x;
    const int jj  = tid >> 4;
    const int kc  = (tid >> 2) & 3;
    const int sg  = tid & 3;
    const size_t idx = (size_t)b * 1024 + (size_t)jj * NK + k0 + kc;

    float s = 0.0f;
    #pragma unroll 8
    for (int ss = 0; ss < KSPLIT / 4; ++ss)
        s += part[(size_t)(sg + 4 * ss) * SOUT + idx];
    ls[tid] = s;
    __syncthreads();

    if (sg == 0)
        l2[jj * 4 + kc] = ls[tid] + ls[tid + 1] + ls[tid + 2] + ls[tid + 3];
    __syncthreads();

    if (sg == 0) {
        float sa  = l2[jj * 4 + kc];
        float msq = 0.0f;
        #pragma unroll
        for (int j2 = 0; j2 < NJ; ++j2) {
            float v = l2[j2 * 4 + kc];
            msq += v * v;
        }
        float mag = sqrtf(msq);
        out[idx] = sa * (mag / (1.0f + msq));
    }
}

extern "C" void kernel_launch(void* const* d_in, const int* in_sizes, int n_in,
                              void* d_out, int out_size, void* d_ws, size_t ws_size,
                              hipStream_t stream) {
    const float* x = (const float*)d_in[0];   // (32, 16, 2048) f32
    const float* W = (const float*)d_in[1];   // (1, 2048, 16, 64, 16) f32
    float* out  = (float*)d_out;              // (32, 16, 64) f32

    float*  part = (float*)d_ws;                            // 16 MB
    ushort* xb   = (ushort*)(part + (size_t)KSPLIT * SOUT); // 2 MB

    caps_xprep <<<dim3(128, 2),        256, 0, stream>>>(x, xb);
    caps_mfma  <<<dim3(NJ/JPB, KSPLIT),256, 0, stream>>>(xb, W, part);
    caps_finish<<<512,                 256, 0, stream>>>(part, out);
}

// Round 10
// 199.039 us; speedup vs baseline: 1.4116x; 1.0814x over previous
//
#include <hip/hip_runtime.h>
#include <hip/hip_bf16.h>

// Problem: out[b,j,k] = squash_j( s[b,j,k] ), s = sum_{i<2048,u<16} W[i,j,k,u] x[b,u,i]
// GEMM view: C[m=b(32), n=(j,k)(1024)] = A[m,(i,u)] B[(i,u),n], K=32768.
// W[i][j][k][u] strides (floats): i:16384, j:1024, k:16, u:1
// x[b][u][i]    strides (floats): b:32768, u:2048, i:1
//
// R10: R8's diagnostic + R9's failure isolated the true bottleneck: at
// VGPR=48 the compiler serializes the K-loop (load -> waitcnt -> use, ~1
// outstanding load/wave, ~1000 cy/step), so occupancy knobs were null
// (R2/R3/R9). Fix = per-wave ILP: explicit register double-buffered
// prefetch, chunk = 4 K-steps, issue chunk c+1's 16 loads before computing
// chunk c (16-32 loads in flight/wave). launch_bounds(256,2) lifts the VGPR
// cap (~160 needed; 8 waves/CU preserved). Shell = R7 (KSPLIT=32, 4MB part,
// proven xprep/finish).

#define B_SZ   32
#define IC     2048
#define NJ     16
#define NK     64
#define SOUT   (B_SZ*NJ*NK)      // 32768
#define KSTEPS 1024              // K-steps; each covers kdim=32 = (2 i's x 16 u)
#define KSPLIT 32                // K-splits (grid = NJ x KSPLIT = 512 blocks)
#define SPW    (KSTEPS/KSPLIT)   // 32 steps per block
#define CH     4                 // steps per chunk
#define CW     ((size_t)CH*2*16384)  // W float-stride per chunk
#define CX     ((size_t)CH*1024)     // xb ushort-stride per chunk

typedef float  v4f __attribute__((ext_vector_type(4)));
typedef short  v8s __attribute__((ext_vector_type(8)));
typedef uint   v4u __attribute__((ext_vector_type(4)));

// pack 2 f32 -> 1 dword of 2 bf16 (RNE); lowers to v_cvt_pk_bf16_f32
static __device__ inline uint pk2(float a, float b) {
    __hip_bfloat162 h = __float22bfloat162_rn(make_float2(a, b));
    uint r;
    __builtin_memcpy(&r, &h, 4);
    return r;
}

// issue one chunk's loads (8 W dwordx4 + 8 xb dwordx4), no waits
static __device__ __forceinline__
void load_chunk(const float* wp, const ushort* xp, v4f (&w)[8], v8s (&a)[8]) {
    #pragma unroll
    for (int t = 0; t < CH; ++t) {
        w[2*t]   = *(const v4f*)(wp + (size_t)t * 2 * 16384);
        w[2*t+1] = *(const v4f*)(wp + (size_t)t * 2 * 16384 + 4);
        a[2*t]   = *(const v8s*)(xp + (size_t)t * 1024);
        a[2*t+1] = *(const v8s*)(xp + (size_t)t * 1024 + 512);
    }
}

// consume one chunk: cvt_pk -> B-frags, 2 MFMA per step
static __device__ __forceinline__
void comp_chunk(const v4f (&w)[8], const v8s (&a)[8], v4f& acc0, v4f& acc1) {
    #pragma unroll
    for (int t = 0; t < CH; ++t) {
        v4u bu;
        bu[0] = pk2(w[2*t].x,   w[2*t].y);
        bu[1] = pk2(w[2*t].z,   w[2*t].w);
        bu[2] = pk2(w[2*t+1].x, w[2*t+1].y);
        bu[3] = pk2(w[2*t+1].z, w[2*t+1].w);
        v8s bb;
        __builtin_memcpy(&bb, &bu, 16);
        acc0 = __builtin_amdgcn_mfma_f32_16x16x32_bf16(a[2*t],   bb, acc0, 0, 0, 0);
        acc1 = __builtin_amdgcn_mfma_f32_16x16x32_bf16(a[2*t+1], bb, acc1, 0, 0, 0);
    }
}

// ---------------------------------------------------------------------------
// xprep v2 (unchanged from R7): full-line x reads + LDS transpose, coalesced
// xb writes. xb flat: [step(1024)][mt(2)][lane(64)][jj(8)] bf16; value =
//   bf16( x[b = mt*16+(lane&15)][u = (q&1)*8+jj][i = 2*step+(q>>1)] ), q=lane>>4.
// ---------------------------------------------------------------------------
__global__ __launch_bounds__(256)
void caps_xprep(const float* __restrict__ x, ushort* __restrict__ xb) {
    __shared__ ushort tile[256 * 18];    // 9 KB
    const int t  = threadIdx.x;
    const int i0 = blockIdx.x * 16;      // 0..2032
    const int mt = blockIdx.y;           // 0..1

    {
        const int r2 = t;                          // row = b_local*16 + u
        const float* xp = x + (size_t)(mt * 256 + r2) * IC + i0;
        v4f f0 = *(const v4f*)(xp);
        v4f f1 = *(const v4f*)(xp + 4);
        v4f f2 = *(const v4f*)(xp + 8);
        v4f f3 = *(const v4f*)(xp + 12);
        uint d[8] = {pk2(f0.x, f0.y), pk2(f0.z, f0.w), pk2(f1.x, f1.y), pk2(f1.z, f1.w),
                     pk2(f2.x, f2.y), pk2(f2.z, f2.w), pk2(f3.x, f3.y), pk2(f3.z, f3.w)};
        const int swz = ((r2 >> 3) & 7) << 1;      // even -> dword pairs stay intact
        #pragma unroll
        for (int c = 0; c < 8; ++c)
            *(uint*)&tile[r2 * 18 + ((2 * c) ^ swz)] = d[c];
    }
    __syncthreads();

    #pragma unroll
    for (int rr = 0; rr < 2; ++rr) {
        const int idx   = rr * 256 + t;
        const int stepl = idx >> 6;                // 0..7
        const int lane  = idx & 63;
        const int q  = lane >> 4;
        const int bl = lane & 15;
        const int il = 2 * stepl + (q >> 1);       // 0..15
        const int rb = bl * 16 + (q & 1) * 8;      // row base (mult of 8)
        const int swz = ((rb >> 3) & 7) << 1;      // constant over jj
        ushort v[8];
        #pragma unroll
        for (int jj = 0; jj < 8; ++jj)
            v[jj] = tile[(rb + jj) * 18 + (il ^ swz)];
        const int stepg = blockIdx.x * 8 + stepl;
        *(v8s*)(xb + (size_t)stepg * 1024 + mt * 512 + lane * 8) = *(const v8s*)v;
    }
}

// ---------------------------------------------------------------------------
// main: block = (j, split), 256 thr = 4 waves; wave wv = k'-tile (16 k's).
// 32 steps = 8 chunks of 4; register double-buffer (sets A/B), prefetch
// chunk c+1 before computing chunk c. Schedule:
//   L0(A); { L1(B) C0(A) L2(A) C1(B) } x3 ; L7(B) C6(A) C7(B)
// B-operand layout: lane holds B[kk = (lane>>4)*8 + jj][n = lane&15];
//   W addr: i = 2*step + (q>>1), u = (q&1)*8 + jj (8 consecutive floats).
// ---------------------------------------------------------------------------
__global__ __launch_bounds__(256, 2)
void caps_mfma(const ushort* __restrict__ xb, const float* __restrict__ W,
               float* __restrict__ part) {
    const int tid   = threadIdx.x;
    const int wv    = tid >> 6;       // k'-tile 0..3
    const int lane  = tid & 63;
    const int j     = blockIdx.x;     // 0..15
    const int split = blockIdx.y;     // 0..KSPLIT-1
    const int n     = lane & 15;
    const int q     = lane >> 4;
    const int step0 = split * SPW;

    v4f acc0 = {0.f, 0.f, 0.f, 0.f};
    v4f acc1 = {0.f, 0.f, 0.f, 0.f};

    const float*  wp = W + (size_t)(2 * step0 + (q >> 1)) * 16384
                         + (size_t)j * 1024 + (size_t)(wv * 16 + n) * 16 + (q & 1) * 8;
    const ushort* xp = xb + (size_t)step0 * 1024 + (size_t)lane * 8;

    v4f wA[8], wB[8];
    v8s aA[8], aB[8];

    load_chunk(wp, xp, wA, aA); wp += CW; xp += CX;
    #pragma unroll 1
    for (int c = 0; c < 3; ++c) {
        load_chunk(wp, xp, wB, aB); wp += CW; xp += CX;
        comp_chunk(wA, aA, acc0, acc1);
        load_chunk(wp, xp, wA, aA); wp += CW; xp += CX;
        comp_chunk(wB, aB, acc0, acc1);
    }
    load_chunk(wp, xp, wB, aB);
    comp_chunk(wA, aA, acc0, acc1);
    comp_chunk(wB, aB, acc0, acc1);

    // C/D layout: col = lane&15 = n (k'), row = q*4 + reg = m (b).
    // part[split][b][j][k] : k = wv*16 + n
    float* pp = part + (size_t)split * SOUT + (size_t)j * NK + wv * 16 + n;
    #pragma unroll
    for (int r = 0; r < 4; ++r) {
        int m = q * 4 + r;
        pp[(size_t)m * 1024]        = acc0[r];
        pp[(size_t)(m + 16) * 1024] = acc1[r];
    }
}

// ---------------------------------------------------------------------------
// finish (unchanged from R7): sum K-splits + squash over j, 512 blocks.
// block -> (b = bid>>4, k0 = (bid&15)*4); thread -> (jj = tid>>4,
// kc = (tid>>2)&3, sg = tid&3). Each thread sums 8 splits -> LDS reduce over
// sg -> squash over jj.
// ---------------------------------------------------------------------------
__global__ __launch_bounds__(256)
void caps_finish(const float* __restrict__ part, float* __restrict__ out) {
    __shared__ float ls[256];
    __shared__ float l2[64];
    const int bid = blockIdx.x;
    const int b   = bid >> 4;
    const int k0  = (bid & 15) * 4;
    const int tid = threadIdx.x;
    const int jj  = tid >> 4;
    const int kc  = (tid >> 2) & 3;
    const int sg  = tid & 3;
    const size_t idx = (size_t)b * 1024 + (size_t)jj * NK + k0 + kc;

    float s = 0.0f;
    #pragma unroll
    for (int ss = 0; ss < KSPLIT / 4; ++ss)
        s += part[(size_t)(sg + 4 * ss) * SOUT + idx];
    ls[tid] = s;
    __syncthreads();

    if (sg == 0)
        l2[jj * 4 + kc] = ls[tid] + ls[tid + 1] + ls[tid + 2] + ls[tid + 3];
    __syncthreads();

    if (sg == 0) {
        float sa  = l2[jj * 4 + kc];
        float msq = 0.0f;
        #pragma unroll
        for (int j2 = 0; j2 < NJ; ++j2) {
            float v = l2[j2 * 4 + kc];
            msq += v * v;
        }
        float mag = sqrtf(msq);
        out[idx] = sa * (mag / (1.0f + msq));
    }
}

extern "C" void kernel_launch(void* const* d_in, const int* in_sizes, int n_in,
                              void* d_out, int out_size, void* d_ws, size_t ws_size,
                              hipStream_t stream) {
    const float* x = (const float*)d_in[0];   // (32, 16, 2048) f32
    const float* W = (const float*)d_in[1];   // (1, 2048, 16, 64, 16) f32
    float* out  = (float*)d_out;              // (32, 16, 64) f32

    float*  part = (float*)d_ws;                            // 4 MB
    ushort* xb   = (ushort*)(part + (size_t)KSPLIT * SOUT); // 2 MB

    caps_xprep <<<dim3(128, 2),     256, 0, stream>>>(x, xb);
    caps_mfma  <<<dim3(NJ, KSPLIT), 256, 0, stream>>>(xb, W, part);
    caps_finish<<<512,              256, 0, stream>>>(part, out);
}